// Round 1
// baseline (1910.768 us; speedup 1.0000x reference)
//
#include <hip/hip_runtime.h>

// DeepRLSNet: batched RLS. B=64, N=T=2000, TAPS=64.
//
// R13 = R12's two-steps-per-round Sherman-Morrison (bitwise QT==Q^T dual
// rank-1 updates) folded from 4 waves into ONE wave per batch:
//   lane = (quad i, quarter q) owns rows 4i..4i+3, cols 16q..16q+16 of Q,QT.
// The quad_reduce tree, quarter-chain fma order, scalar section and update
// grouping are bit-identical to R12 — only the thread mapping changed.
// Rationale (rocprof): VALUBusy 9.8%, 0 bank conflicts -> ~90% of cycles are
// barrier-convoy + LDS-pipe serialization across the 4 lockstepped waves.
// One wave needs NO s_barrier (same-wave DS pipe is in-order; compiler emits
// the lgkmcnt waits) and 1/4 the DS-pipe traffic per round.
// d/lam LDS staging replaced by register prefetch of bit-identical values.

#define B_ 64
#define N_ 2000
#define TAPS_ 64
#define STEPS_ 2000
#define VSTF_ 68   // floats per exchanged vector in LDS (64 + pad)

typedef float f2 __attribute__((ext_vector_type(2)));

__device__ __forceinline__ f2 pk2(float v) { f2 r; r.x = v; r.y = v; return r; }

__device__ __forceinline__ float clipl(float v) {
    return fminf(fmaxf(v, 1e-4f), 0.9999f);
}

// sum over the 4 q-lanes of a quad via DPP quad_perm (identical to R12).
__device__ __forceinline__ float quad_reduce(float v) {
    int t1 = __builtin_amdgcn_update_dpp(__float_as_int(v), __float_as_int(v),
                                         0xB1, 0xF, 0xF, false);   // xor 1
    v += __int_as_float(t1);
    int t2 = __builtin_amdgcn_update_dpp(__float_as_int(v), __float_as_int(v),
                                         0x4E, 0xF, 0xF, false);   // xor 2
    v += __int_as_float(t2);
    return v;   // bitwise-identical in all 4 lanes of the quad
}

__device__ __forceinline__ float rcp_nr(float v) {
    float r = __builtin_amdgcn_rcpf(v);
    float e = fmaf(-v, r, 1.0f);
    return fmaf(r, e, r);
}

__global__ __launch_bounds__(64, 1) void rls_kernel(
    const float* __restrict__ x_seq,   // [B, N, TAPS]
    const float* __restrict__ d_seq,   // [B, N]
    const float* __restrict__ lambdas, // [T]
    float* __restrict__ y_out,         // [B, N]
    float* __restrict__ w_out)         // [B, TAPS]
{
    const int b    = blockIdx.x;
    const int lane = threadIdx.x;     // 0..63
    const int i4   = lane >> 2;       // quad: owns rows 4*i4 .. 4*i4+3
    const int q    = lane & 3;        // quarter (16-col slice)
    const int qb   = q << 4;
    const int row0 = i4 << 2;

    // exchange buffers only; no barrier — same-wave DS ordering suffices.
    __shared__ __align__(16) float bufs[2][4][VSTF_];

    const float* xb = x_seq + (size_t)b * N_ * TAPS_;
    const float* db = d_seq + (size_t)b * N_;

    // state: 4 quarter-rows each of Q and QT per lane; w quarter replica.
    f2 Q[4][8], QT[4][8], w[8];
    #pragma unroll
    for (int k = 0; k < 4; ++k) {
        #pragma unroll
        for (int j = 0; j < 8; ++j) {
            const int c0 = qb + 2*j, r = row0 + k;
            Q[k][j].x = (c0     == r) ? 1.0f : 0.0f;
            Q[k][j].y = (c0 + 1 == r) ? 1.0f : 0.0f;
            QT[k][j]  = Q[k][j];
        }
    }
    #pragma unroll
    for (int j = 0; j < 8; ++j) w[j] = pk2(0.0f);
    float sig = 1.0f;   // P = sig * Q

    auto loadrow = [&](f2 (&dst)[8], int row) {
        const float4* p = (const float4*)(xb + (size_t)row * TAPS_ + qb);
        #pragma unroll
        for (int j4 = 0; j4 < 4; ++j4) {
            const float4 v = p[j4];
            dst[2*j4].x   = v.x; dst[2*j4].y   = v.y;
            dst[2*j4+1].x = v.z; dst[2*j4+1].y = v.w;
        }
    };

    // two x row-pairs, rotated; round m refills its own pair for round m+2
    // (issued after the last x0/x1 read -> ~1.4-round gap before use).
    f2 xA[8], xB[8], xC[8], xD[8];
    loadrow(xA, 0); loadrow(xB, 1); loadrow(xC, 2); loadrow(xD, 3);

    // lam/d register prefetch, 2-slot ring (pair passed BY VALUE to round,
    // so the slot can be reloaded mid-round without WAR).
    float2 lamS[2], dS[2];
    lamS[0] = *(const float2*)(lambdas + 0);
    lamS[1] = *(const float2*)(lambdas + 2);
    dS[0]   = *(const float2*)(db + 0);
    dS[1]   = *(const float2*)(db + 2);

    int par = 0;

    auto round = [&](int t, f2 (&x0)[8], f2 (&x1)[8],
                     float2 lam_pair, float2 d_pair,
                     float2* lam_slot, float2* d_slot)
    {
        // ---- phase-1: 16 row-dot partial chains (4 rows x {Qx,xQ,u,v}) ----
        f2 cQx[4], cxQ[4], cu[4], cv[4];
        #pragma unroll
        for (int k = 0; k < 4; ++k) {
            cQx[k] = pk2(0.f); cxQ[k] = pk2(0.f);
            cu[k]  = pk2(0.f); cv[k]  = pk2(0.f);
        }
        #pragma unroll
        for (int j = 0; j < 8; ++j) {
            #pragma unroll
            for (int k = 0; k < 4; ++k) {
                cQx[k] = __builtin_elementwise_fma(Q[k][j],  x0[j], cQx[k]);
                cxQ[k] = __builtin_elementwise_fma(QT[k][j], x0[j], cxQ[k]);
                cu[k]  = __builtin_elementwise_fma(Q[k][j],  x1[j], cu[k]);
                cv[k]  = __builtin_elementwise_fma(QT[k][j], x1[j], cv[k]);
            }
        }
        float qxr[4], xqr[4], ur[4], vr[4];
        #pragma unroll
        for (int k = 0; k < 4; ++k) {
            qxr[k] = quad_reduce(cQx[k].x + cQx[k].y);
            xqr[k] = quad_reduce(cxQ[k].x + cxQ[k].y);
            ur[k]  = quad_reduce(cu[k].x + cu[k].y);
            vr[k]  = quad_reduce(cv[k].x + cv[k].y);
        }
        // lane (i4,q) writes vec q's 4 row values (rows 4*i4..4*i4+3)
        {
            float4 wv;
            wv.x = (q==0) ? qxr[0] : (q==1) ? xqr[0] : (q==2) ? ur[0] : vr[0];
            wv.y = (q==0) ? qxr[1] : (q==1) ? xqr[1] : (q==2) ? ur[1] : vr[1];
            wv.z = (q==0) ? qxr[2] : (q==1) ? xqr[2] : (q==2) ? ur[2] : vr[2];
            wv.w = (q==0) ? qxr[3] : (q==1) ? xqr[3] : (q==2) ? ur[3] : vr[3];
            *(float4*)&bufs[par][q][row0] = wv;
        }

        // ---- w dots while the write drains ----
        f2 wy02 = pk2(0.f), wy12 = pk2(0.f);
        #pragma unroll
        for (int j = 0; j < 8; ++j) {
            wy02 = __builtin_elementwise_fma(w[j], x0[j], wy02);
            wy12 = __builtin_elementwise_fma(w[j], x1[j], wy12);
        }
        const float wy0 = quad_reduce(wy02.x + wy02.y);
        const float wy1 = quad_reduce(wy12.x + wy12.y);

        // ---- read back quarter slices of Qx, xQ, u, v (same wave: the DS
        // pipe is in-order, compiler inserts the lgkmcnt before first use) ----
        f2 Qxq[8], xQq[8], uq[8], vq[8];
        {
            const float4* p0 = (const float4*)&bufs[par][0][qb];
            const float4* p1 = (const float4*)&bufs[par][1][qb];
            const float4* p2 = (const float4*)&bufs[par][2][qb];
            const float4* p3 = (const float4*)&bufs[par][3][qb];
            #pragma unroll
            for (int j4 = 0; j4 < 4; ++j4) {
                const float4 v0 = p0[j4], v1 = p1[j4], v2 = p2[j4], v3 = p3[j4];
                Qxq[2*j4].x=v0.x; Qxq[2*j4].y=v0.y; Qxq[2*j4+1].x=v0.z; Qxq[2*j4+1].y=v0.w;
                xQq[2*j4].x=v1.x; xQq[2*j4].y=v1.y; xQq[2*j4+1].x=v1.z; xQq[2*j4+1].y=v1.w;
                uq [2*j4].x=v2.x; uq [2*j4].y=v2.y; uq [2*j4+1].x=v2.z; uq [2*j4+1].y=v2.w;
                vq [2*j4].x=v3.x; vq [2*j4].y=v3.y; vq [2*j4+1].x=v3.z; vq [2*j4+1].y=v3.w;
            }
        }
        par ^= 1;

        // ---- post dots: pd0=x0.Qx, a=x1.xQ, bb=x1.Qx, c2=x1.u ----
        f2 pda = pk2(0.f), aa = pk2(0.f), bba = pk2(0.f), cca = pk2(0.f);
        #pragma unroll
        for (int j = 0; j < 8; ++j) {
            pda = __builtin_elementwise_fma(x0[j], Qxq[j], pda);
            aa  = __builtin_elementwise_fma(x1[j], xQq[j], aa);
            bba = __builtin_elementwise_fma(x1[j], Qxq[j], bba);
            cca = __builtin_elementwise_fma(x1[j], uq[j],  cca);
        }
        const float pd0 = quad_reduce(pda.x + pda.y);
        const float a   = quad_reduce(aa.x + aa.y);
        const float bb  = quad_reduce(bba.x + bba.y);
        const float c2  = quad_reduce(cca.x + cca.y);

        // ---- prefetch round m+2 inputs (x0/x1 fully consumed above) ----
        if (t + 5 < N_) {
            loadrow(x0, t + 4);
            loadrow(x1, t + 5);
            *lam_slot = *(const float2*)(lambdas + t + 4);
            *d_slot   = *(const float2*)(db + t + 4);
        }

        // ---- scalars (R11/R12 op order, bitwise identical) ----
        const float lc0 = clipl(lam_pair.x), lr0 = rcp_nr(lc0);
        const float lc1 = clipl(lam_pair.y), lr1 = rcp_nr(lc1);

        const float den0 = fmaf(sig, pd0, lc0);
        const float s0   = sig * rcp_nr(den0);
        const float err0 = d_pair.x - wy0;
        const float es0  = s0 * err0;
        const float sa   = s0 * a;
        const float sb   = s0 * bb;

        const float sig1 = sig * lr0;
        const float pd1  = fmaf(-sa, bb, c2);
        const float den1 = fmaf(sig1, pd1, lc1);
        const float s1   = sig1 * rcp_nr(den1);
        const float y1   = fmaf(es0, bb, wy1);
        const float err1 = d_pair.y - y1;
        const float es1  = s1 * err1;
        sig = sig1 * lr1;

        if (lane == 0)
            *(float2*)(y_out + (size_t)b * N_ + t) = make_float2(wy0, y1);

        // ---- explicit dual rank-1 updates (bitwise QT == Q^T preserved) ----
        const f2 nsa  = pk2(-sa);
        const f2 nsb  = pk2(-sb);
        const f2 s0v  = pk2(s0);
        const f2 s1v  = pk2(s1);
        const f2 es0v = pk2(es0);
        const f2 es1v = pk2(es1);

        // row-independent vectors, computed once (same bits as R12's per-j)
        f2 Qx1[8], xQ1[8], tq0v[8], tq1v[8];
        #pragma unroll
        for (int j = 0; j < 8; ++j) {
            Qx1[j]  = __builtin_elementwise_fma(nsa, Qxq[j], uq[j]);
            xQ1[j]  = __builtin_elementwise_fma(nsb, xQq[j], vq[j]);
            tq0v[j] = s0v * Qxq[j];
            tq1v[j] = s1v * Qx1[j];
            w[j] = __builtin_elementwise_fma(Qxq[j], es0v, w[j]);
            w[j] = __builtin_elementwise_fma(Qx1[j], es1v, w[j]);
        }
        #pragma unroll
        for (int k = 0; k < 4; ++k) {
            const float qx1r = fmaf(-sa, qxr[k], ur[k]);
            const float xq1r = fmaf(-sb, xqr[k], vr[k]);
            const f2 ntr0  = pk2(-(s0 * qxr[k]));
            const f2 ntr1  = pk2(-(s1 * qx1r));
            const f2 nxqr  = pk2(-xqr[k]);
            const f2 nxq1r = pk2(-xq1r);
            #pragma unroll
            for (int j = 0; j < 8; ++j) {
                Q[k][j]  = __builtin_elementwise_fma(ntr0, xQq[j], Q[k][j]);
                Q[k][j]  = __builtin_elementwise_fma(ntr1, xQ1[j], Q[k][j]);
                QT[k][j] = __builtin_elementwise_fma(tq0v[j], nxqr,  QT[k][j]);
                QT[k][j] = __builtin_elementwise_fma(tq1v[j], nxq1r, QT[k][j]);
            }
        }
    };

    // 1000 rounds; prefetch guard (t+5 < N_) handles the tail rounds.
    for (int t = 0; t < STEPS_; t += 4) {
        round(t,     xA, xB, lamS[0], dS[0], &lamS[0], &dS[0]);
        round(t + 2, xC, xD, lamS[1], dS[1], &lamS[1], &dS[1]);
    }

    // ---- final weights: lanes 0..3 (quad 0) hold a full replica across q ----
    if (i4 == 0) {
        float4* wo = (float4*)(w_out + (size_t)b * TAPS_ + qb);
        #pragma unroll
        for (int j4 = 0; j4 < 4; ++j4)
            wo[j4] = make_float4(w[2*j4].x, w[2*j4].y, w[2*j4+1].x, w[2*j4+1].y);
    }
}

extern "C" void kernel_launch(void* const* d_in, const int* in_sizes, int n_in,
                              void* d_out, int out_size, void* d_ws, size_t ws_size,
                              hipStream_t stream) {
    const float* x_seq   = (const float*)d_in[0];
    const float* d_seq   = (const float*)d_in[1];
    const float* lambdas = (const float*)d_in[2];

    float* y_out = (float*)d_out;                      // B*N floats
    float* w_out = (float*)d_out + (size_t)B_ * N_;    // B*TAPS floats

    rls_kernel<<<B_, 64, 0, stream>>>(x_seq, d_seq, lambdas, y_out, w_out);
}

// Round 2
// 1300.982 us; speedup vs baseline: 1.4687x; 1.4687x over previous
//
#include <hip/hip_runtime.h>

// DeepRLSNet: batched RLS. B=64, N=T=2000, TAPS=64.
//
// R14 = R12 (two-steps-per-round Sherman-Morrison, bitwise QT==Q^T dual
// rank-1 updates, 1 barrier/round, parity-double-buffered LDS exchange)
// with the per-batch work split across EIGHT waves instead of four:
//   group A (tid 0..255):  owns Q rows + w  -> computes Qx, u, wy; updates Q, w
//   group B (tid 256..511): owns QT rows    -> computes xQ, v;      updates QT
// Within each group the (r = t>>2, q = t&3) row/quarter mapping, quad_reduce
// DPP tree, fma chain orders, LDS exchange layout and scalar section are
// bit-identical to R12 -> output bits unchanged (absmax canary 0.015625).
// Both groups replicate the scalar chain from the same LDS bits, so sig/s0/s1
// agree bitwise and the QT==Q^T invariant is preserved.
//
// Rationale (R12/R13 post-mortems): R12 = 4 lockstepped waves, 1 wave/SIMD,
// ~60% dependency-bubble stall (VALUBusy 39% of active SIMDs). R13 = 1 wave,
// issue-bound (72% busy on its lone SIMD), 1.9x worse. R14 keeps R12's
// parallel issue but lands 2 waves/SIMD (one A + one B, complementary mixes)
// so each SIMD has a second independent stream to fill the bubbles between
// barriers. Barrier count unchanged (1/round).

#define B_ 64
#define N_ 2000
#define TAPS_ 64
#define STEPS_ 2000
#define VST_ 72   // padded LDS vector stride (R12 layout; writes hit 32 distinct banks)

typedef float f2 __attribute__((ext_vector_type(2)));

__device__ __forceinline__ f2 pk2(float v) { f2 r; r.x = v; r.y = v; return r; }

__device__ __forceinline__ void lds_barrier() {
    // LDS-only fence + barrier: global (vmcnt) prefetch stays in flight.
    asm volatile("s_waitcnt lgkmcnt(0)\n\ts_barrier" ::: "memory");
}

__device__ __forceinline__ float clipl(float v) {
    return fminf(fmaxf(v, 1e-4f), 0.9999f);
}

// sum over the 4 q-lanes of a quad via DPP quad_perm (identical to R12).
__device__ __forceinline__ float quad_reduce(float v) {
    int t1 = __builtin_amdgcn_update_dpp(__float_as_int(v), __float_as_int(v),
                                         0xB1, 0xF, 0xF, false);   // xor 1
    v += __int_as_float(t1);
    int t2 = __builtin_amdgcn_update_dpp(__float_as_int(v), __float_as_int(v),
                                         0x4E, 0xF, 0xF, false);   // xor 2
    v += __int_as_float(t2);
    return v;   // bitwise-identical in all 4 lanes of the quad
}

// 1/v via v_rcp_f32 + one Newton step (~0.5 ulp). Identical to R12.
__device__ __forceinline__ float rcp_nr(float v) {
    float r = __builtin_amdgcn_rcpf(v);
    float e = fmaf(-v, r, 1.0f);
    return fmaf(r, e, r);
}

__global__ __launch_bounds__(512, 1) void rls_kernel(
    const float* __restrict__ x_seq,   // [B, N, TAPS]
    const float* __restrict__ d_seq,   // [B, N]
    const float* __restrict__ lambdas, // [T]
    float* __restrict__ y_out,         // [B, N]
    float* __restrict__ w_out)         // [B, TAPS]
{
    const int b   = blockIdx.x;
    const int tid = threadIdx.x;      // 0..511
    const int t4  = tid & 255;        // index within group
    const int r   = t4 >> 2;          // row 0..63
    const int q   = t4 & 3;           // quarter 0..3
    const int qb  = q << 4;

    // [parity][vec][VST_], vec: 0=Qx 1=xQ 2=u 3=v  (R12 layout)
    __shared__ __align__(16) float  bufs[2][4][VST_];
    __shared__ __align__(16) float  d_lds[STEPS_];
    __shared__ __align__(16) float2 lam2[STEPS_];   // {clip(lam), rcp_nr(clip(lam))}

    const float* xb = x_seq + (size_t)b * N_ * TAPS_;
    const float* db = d_seq + (size_t)b * N_;

    for (int idx = tid; idx < STEPS_; idx += 512) {
        d_lds[idx] = db[idx];
        const float lc = clipl(lambdas[idx]);
        lam2[idx] = make_float2(lc, rcp_nr(lc));
    }

    auto unpack4 = [](f2* dst, float4 v) {
        dst[0].x = v.x; dst[0].y = v.y; dst[1].x = v.z; dst[1].y = v.w;
    };

    if (tid < 256) {
        // ================= group A: Q rows + w =================
        f2 Q[8], w[8];
        #pragma unroll
        for (int j = 0; j < 8; ++j) {
            Q[j].x = (qb + 2*j     == r) ? 1.0f : 0.0f;
            Q[j].y = (qb + 2*j + 1 == r) ? 1.0f : 0.0f;
            w[j]   = pk2(0.0f);
        }
        float sig = 1.0f;   // P = sig * Q

        f2 xA[8], xB[8], xC[8], xD[8];
        {
            const float4* v0 = (const float4*)(xb + qb);
            const float4* v1 = (const float4*)(xb + TAPS_ + qb);
            #pragma unroll
            for (int j4 = 0; j4 < 4; ++j4) {
                unpack4(&xA[2*j4], v0[j4]);
                unpack4(&xB[2*j4], v1[j4]);
            }
        }
        const float* xp = xb + 2 * TAPS_ + qb;   // prefetch ptr (row t+2)

        lds_barrier();   // d_lds / lam2 visible

        auto round = [&](int t, f2 (&x0)[8], f2 (&x1)[8],
                         f2 (&xp0)[8], f2 (&xp1)[8], int par, bool pf) {
            // ---- own dot families: Qx (x0), u (x1) — write ASAP ----
            f2 qx2 = pk2(0.f), u2 = pk2(0.f);
            #pragma unroll
            for (int j = 0; j < 8; ++j) {
                qx2 = __builtin_elementwise_fma(Q[j], x0[j], qx2);
                u2  = __builtin_elementwise_fma(Q[j], x1[j], u2);
            }
            const float qxr = quad_reduce(qx2.x + qx2.y);
            const float ur  = quad_reduce(u2.x + u2.y);
            if (q < 2) bufs[par][q << 1][r] = (q == 0) ? qxr : ur;   // vec0/vec2

            // ---- w dots while the write drains (R12 chain order) ----
            f2 wy02 = pk2(0.f), wy12 = pk2(0.f);
            #pragma unroll
            for (int j = 0; j < 8; ++j) {
                wy02 = __builtin_elementwise_fma(w[j], x0[j], wy02);
                wy12 = __builtin_elementwise_fma(w[j], x1[j], wy12);
            }
            const float wy0 = quad_reduce(wy02.x + wy02.y);
            const float wy1 = quad_reduce(wy12.x + wy12.y);

            lds_barrier();

            const float2 l0 = lam2[t];
            const float2 l1 = lam2[t + 1];
            const float2 dd = *(const float2*)&d_lds[t];

            // ---- prefetch next round's x rows (rides across barriers) ----
            if (pf) {
                const float4* v0 = (const float4*)xp;
                const float4* v1 = (const float4*)(xp + TAPS_);
                #pragma unroll
                for (int j4 = 0; j4 < 4; ++j4) {
                    unpack4(&xp0[2*j4], v0[j4]);
                    unpack4(&xp1[2*j4], v1[j4]);
                }
                xp += 2 * TAPS_;
            }

            // ---- read back quarters of Qx, xQ, u, v ----
            f2 Qxq[8], xQq[8], uq[8], vq[8];
            {
                const float4* p0 = (const float4*)(&bufs[par][0][qb]);
                const float4* p1 = (const float4*)(&bufs[par][1][qb]);
                const float4* p2 = (const float4*)(&bufs[par][2][qb]);
                const float4* p3 = (const float4*)(&bufs[par][3][qb]);
                #pragma unroll
                for (int j4 = 0; j4 < 4; ++j4) {
                    unpack4(&Qxq[2*j4], p0[j4]);
                    unpack4(&xQq[2*j4], p1[j4]);
                    unpack4(&uq [2*j4], p2[j4]);
                    unpack4(&vq [2*j4], p3[j4]);
                }
            }

            // ---- post-barrier dots (R12 chains) ----
            f2 pd2 = pk2(0.f), a2 = pk2(0.f), bb2 = pk2(0.f), c22 = pk2(0.f);
            #pragma unroll
            for (int j = 0; j < 8; ++j) {
                pd2 = __builtin_elementwise_fma(x0[j], Qxq[j], pd2);
                a2  = __builtin_elementwise_fma(x1[j], xQq[j], a2);
                bb2 = __builtin_elementwise_fma(x1[j], Qxq[j], bb2);
                c22 = __builtin_elementwise_fma(x1[j], uq[j],  c22);
            }
            const float pd0 = quad_reduce(pd2.x + pd2.y);
            const float a   = quad_reduce(a2.x + a2.y);
            const float bb  = quad_reduce(bb2.x + bb2.y);
            const float c2  = quad_reduce(c22.x + c22.y);

            // ---- scalars (R12 op order, full chain incl. error terms) ----
            const float den0 = fmaf(sig, pd0, l0.x);
            const float s0   = sig * rcp_nr(den0);
            const float err0 = dd.x - wy0;
            const float es0  = s0 * err0;
            const float sa   = s0 * a;
            const float sb   = s0 * bb;

            const float sig1 = sig * l0.y;
            const float pd1  = fmaf(-sa, bb, c2);
            const float den1 = fmaf(sig1, pd1, l1.x);
            const float s1   = sig1 * rcp_nr(den1);
            const float y1   = fmaf(es0, bb, wy1);
            const float err1 = dd.y - y1;
            const float es1  = s1 * err1;
            sig = sig1 * l1.y;

            if (t4 == 0)
                *(float2*)(y_out + (size_t)b * N_ + t) = make_float2(wy0, y1);

            // ---- A-side updates: w (two rank-1 adds) and Q ----
            const float qx1r = fmaf(-sa, qxr, ur);
            const f2 nsa  = pk2(-sa);
            const f2 nsb  = pk2(-sb);
            const f2 es0v = pk2(es0);
            const f2 es1v = pk2(es1);
            const f2 ntr0 = pk2(-(s0 * qxr));
            const f2 ntr1 = pk2(-(s1 * qx1r));

            #pragma unroll
            for (int j = 0; j < 8; ++j) {
                const f2 Qx1 = __builtin_elementwise_fma(nsa, Qxq[j], uq[j]);
                const f2 xQ1 = __builtin_elementwise_fma(nsb, xQq[j], vq[j]);
                w[j] = __builtin_elementwise_fma(Qxq[j], es0v, w[j]);
                w[j] = __builtin_elementwise_fma(Qx1,    es1v, w[j]);
                Q[j] = __builtin_elementwise_fma(ntr0, xQq[j], Q[j]);
                Q[j] = __builtin_elementwise_fma(ntr1, xQ1,    Q[j]);
            }
        };

        for (int t = 0; t < STEPS_ - 4; t += 4) {
            round(t + 0, xA, xB, xC, xD, 0, true);
            round(t + 2, xC, xD, xA, xB, 1, true);
        }
        round(STEPS_ - 4, xA, xB, xC, xD, 0, true);
        round(STEPS_ - 2, xC, xD, xA, xB, 1, false);

        // final weights: rows r==0 hold a full replica across q
        if (r == 0) {
            float4* wo = (float4*)(w_out + (size_t)b * TAPS_ + qb);
            #pragma unroll
            for (int j4 = 0; j4 < 4; ++j4)
                wo[j4] = make_float4(w[2*j4].x, w[2*j4].y, w[2*j4+1].x, w[2*j4+1].y);
        }
    } else {
        // ================= group B: QT rows =================
        f2 QT[8];
        #pragma unroll
        for (int j = 0; j < 8; ++j) {
            QT[j].x = (qb + 2*j     == r) ? 1.0f : 0.0f;
            QT[j].y = (qb + 2*j + 1 == r) ? 1.0f : 0.0f;
        }
        float sig = 1.0f;

        f2 xA[8], xB[8], xC[8], xD[8];
        {
            const float4* v0 = (const float4*)(xb + qb);
            const float4* v1 = (const float4*)(xb + TAPS_ + qb);
            #pragma unroll
            for (int j4 = 0; j4 < 4; ++j4) {
                unpack4(&xA[2*j4], v0[j4]);
                unpack4(&xB[2*j4], v1[j4]);
            }
        }
        const float* xp = xb + 2 * TAPS_ + qb;

        lds_barrier();   // d_lds / lam2 visible

        auto round = [&](int t, f2 (&x0)[8], f2 (&x1)[8],
                         f2 (&xp0)[8], f2 (&xp1)[8], int par, bool pf) {
            // ---- own dot families: xQ (x0), v (x1) — write ASAP ----
            f2 xq2 = pk2(0.f), v2 = pk2(0.f);
            #pragma unroll
            for (int j = 0; j < 8; ++j) {
                xq2 = __builtin_elementwise_fma(QT[j], x0[j], xq2);
                v2  = __builtin_elementwise_fma(QT[j], x1[j], v2);
            }
            const float xqr = quad_reduce(xq2.x + xq2.y);
            const float vr  = quad_reduce(v2.x + v2.y);
            if (q < 2) bufs[par][(q << 1) | 1][r] = (q == 0) ? xqr : vr; // vec1/vec3

            lds_barrier();

            const float2 l0 = lam2[t];
            const float2 l1 = lam2[t + 1];

            if (pf) {
                const float4* v0 = (const float4*)xp;
                const float4* v1 = (const float4*)(xp + TAPS_);
                #pragma unroll
                for (int j4 = 0; j4 < 4; ++j4) {
                    unpack4(&xp0[2*j4], v0[j4]);
                    unpack4(&xp1[2*j4], v1[j4]);
                }
                xp += 2 * TAPS_;
            }

            f2 Qxq[8], xQq[8], uq[8], vq[8];
            {
                const float4* p0 = (const float4*)(&bufs[par][0][qb]);
                const float4* p1 = (const float4*)(&bufs[par][1][qb]);
                const float4* p2 = (const float4*)(&bufs[par][2][qb]);
                const float4* p3 = (const float4*)(&bufs[par][3][qb]);
                #pragma unroll
                for (int j4 = 0; j4 < 4; ++j4) {
                    unpack4(&Qxq[2*j4], p0[j4]);
                    unpack4(&xQq[2*j4], p1[j4]);
                    unpack4(&uq [2*j4], p2[j4]);
                    unpack4(&vq [2*j4], p3[j4]);
                }
            }

            // ---- post-barrier dots (identical chains/bits to group A) ----
            f2 pd2 = pk2(0.f), a2 = pk2(0.f), bb2 = pk2(0.f), c22 = pk2(0.f);
            #pragma unroll
            for (int j = 0; j < 8; ++j) {
                pd2 = __builtin_elementwise_fma(x0[j], Qxq[j], pd2);
                a2  = __builtin_elementwise_fma(x1[j], xQq[j], a2);
                bb2 = __builtin_elementwise_fma(x1[j], Qxq[j], bb2);
                c22 = __builtin_elementwise_fma(x1[j], uq[j],  c22);
            }
            const float pd0 = quad_reduce(pd2.x + pd2.y);
            const float a   = quad_reduce(a2.x + a2.y);
            const float bb  = quad_reduce(bb2.x + bb2.y);
            const float c2  = quad_reduce(c22.x + c22.y);

            // ---- scalars: shared prefix of R12's chain (same inputs/order
            //      as group A -> bitwise-identical sig/s0/s1/sa/sb) ----
            const float den0 = fmaf(sig, pd0, l0.x);
            const float s0   = sig * rcp_nr(den0);
            const float sa   = s0 * a;
            const float sb   = s0 * bb;

            const float sig1 = sig * l0.y;
            const float pd1  = fmaf(-sa, bb, c2);
            const float den1 = fmaf(sig1, pd1, l1.x);
            const float s1   = sig1 * rcp_nr(den1);
            sig = sig1 * l1.y;

            // ---- B-side update: QT (transposed products, R12 bit order) ----
            const float xq1r = fmaf(-sb, xqr, vr);
            const f2 nsa   = pk2(-sa);
            const f2 s0v   = pk2(s0);
            const f2 s1v   = pk2(s1);
            const f2 nxqr  = pk2(-xqr);
            const f2 nxq1r = pk2(-xq1r);

            #pragma unroll
            for (int j = 0; j < 8; ++j) {
                const f2 Qx1 = __builtin_elementwise_fma(nsa, Qxq[j], uq[j]);
                const f2 tq0 = s0v * Qxq[j];
                const f2 tq1 = s1v * Qx1;
                QT[j] = __builtin_elementwise_fma(tq0, nxqr,  QT[j]);
                QT[j] = __builtin_elementwise_fma(tq1, nxq1r, QT[j]);
            }
        };

        for (int t = 0; t < STEPS_ - 4; t += 4) {
            round(t + 0, xA, xB, xC, xD, 0, true);
            round(t + 2, xC, xD, xA, xB, 1, true);
        }
        round(STEPS_ - 4, xA, xB, xC, xD, 0, true);
        round(STEPS_ - 2, xC, xD, xA, xB, 1, false);
    }
}

extern "C" void kernel_launch(void* const* d_in, const int* in_sizes, int n_in,
                              void* d_out, int out_size, void* d_ws, size_t ws_size,
                              hipStream_t stream) {
    const float* x_seq   = (const float*)d_in[0];
    const float* d_seq   = (const float*)d_in[1];
    const float* lambdas = (const float*)d_in[2];

    float* y_out = (float*)d_out;                      // B*N floats
    float* w_out = (float*)d_out + (size_t)B_ * N_;    // B*TAPS floats

    rls_kernel<<<B_, 512, 0, stream>>>(x_seq, d_seq, lambdas, y_out, w_out);
}

// Round 3
// 941.633 us; speedup vs baseline: 2.0292x; 1.3816x over previous
//
#include <hip/hip_runtime.h>

// DeepRLSNet: batched RLS. B=64, N=T=2000, TAPS=64.
//
// R15 = R12 (best: 1023us; two-steps-per-round Sherman-Morrison, bitwise
// QT==Q^T dual rank-1 updates, 4 waves, 1 barrier/round, parity LDS exchange)
// + two BIT-IDENTICAL schedule changes:
//  (1) FUSED update+next-dots: next round's pre-dots (Qx,xQ,u,v,wy vs rows
//      t+2,t+3) are accumulated inside the update loop right after each
//      Q[j]/QT[j]/w[j] is produced. Same ops, same values, same j-order ->
//      same bits; removes the update->predot serial phase boundary.
//      Reduced row values (qxr/xqr/ur/vr/wy0/wy1) are loop-carried.
//  (2) 4-pair x-prefetch rotation issued 3 pairs ahead (~2.5-round gap,
//      ~6000cy >> ~900cy HBM latency) so no round blocks on vmcnt at entry.
//      (R12 issued mid-round t for use at round t+1 start: ~0.6-round gap.)
// Rationale: R12 rocprof shows ~39% per-active-SIMD VALUBusy -> ~60% stall;
// R13 (1 wave, no barrier) and R14 (8 waves) both regressed -> keep the
// 4-wave shape, attack vmcnt exposure + phase-boundary serialization.
// Canary: absmax must be exactly 0.015625 (bitwise-identical arithmetic).

#define B_ 64
#define N_ 2000
#define TAPS_ 64
#define STEPS_ 2000
#define VST_ 72   // padded LDS vector stride; banks r+8q -> 2-way max (free)

typedef float f2 __attribute__((ext_vector_type(2)));

__device__ __forceinline__ f2 pk2(float v) { f2 r; r.x = v; r.y = v; return r; }

__device__ __forceinline__ void lds_barrier() {
    // LDS-only fence + barrier: global (vmcnt) prefetch stays in flight.
    asm volatile("s_waitcnt lgkmcnt(0)\n\ts_barrier" ::: "memory");
}

__device__ __forceinline__ float clipl(float v) {
    return fminf(fmaxf(v, 1e-4f), 0.9999f);
}

// sum over the 4 q-lanes of a quad via DPP quad_perm (identical to R12).
__device__ __forceinline__ float quad_reduce(float v) {
    int t1 = __builtin_amdgcn_update_dpp(__float_as_int(v), __float_as_int(v),
                                         0xB1, 0xF, 0xF, false);   // xor 1
    v += __int_as_float(t1);
    int t2 = __builtin_amdgcn_update_dpp(__float_as_int(v), __float_as_int(v),
                                         0x4E, 0xF, 0xF, false);   // xor 2
    v += __int_as_float(t2);
    return v;   // bitwise-identical in all 4 lanes of the quad
}

// 1/v via v_rcp_f32 + one Newton step (~0.5 ulp). Identical to R12.
__device__ __forceinline__ float rcp_nr(float v) {
    float r = __builtin_amdgcn_rcpf(v);
    float e = fmaf(-v, r, 1.0f);
    return fmaf(r, e, r);
}

__global__ __launch_bounds__(256, 1) void rls_kernel(
    const float* __restrict__ x_seq,   // [B, N, TAPS]
    const float* __restrict__ d_seq,   // [B, N]
    const float* __restrict__ lambdas, // [T]
    float* __restrict__ y_out,         // [B, N]
    float* __restrict__ w_out)         // [B, TAPS]
{
    const int b   = blockIdx.x;
    const int tid = threadIdx.x;
    const int r   = tid >> 2;    // row 0..63
    const int q   = tid & 3;     // quarter 0..3
    const int qb  = q << 4;

    // [parity][vec][VST_], vec: 0=Qx 1=xQ 2=u 3=v  (R12 layout)
    __shared__ __align__(16) float  bufs[2][4][VST_];
    __shared__ __align__(16) float  d_lds[STEPS_];
    __shared__ __align__(16) float2 lam2[STEPS_];   // {clip(lam), rcp_nr(clip(lam))}

    const float* xb = x_seq + (size_t)b * N_ * TAPS_;
    const float* db = d_seq + (size_t)b * N_;

    for (int idx = tid; idx < STEPS_; idx += 256) {
        d_lds[idx] = db[idx];
        const float lc = clipl(lambdas[idx]);
        lam2[idx] = make_float2(lc, rcp_nr(lc));
    }

    f2 Q[8], QT[8], w[8];
    #pragma unroll
    for (int j = 0; j < 8; ++j) {
        Q[j].x = (qb + 2*j     == r) ? 1.0f : 0.0f;
        Q[j].y = (qb + 2*j + 1 == r) ? 1.0f : 0.0f;
        QT[j] = Q[j];
        w[j]  = pk2(0.0f);
    }
    float sig = 1.0f;   // P = sig * Q

    auto unpack4 = [](f2* dst, float4 v) {
        dst[0].x = v.x; dst[0].y = v.y; dst[1].x = v.z; dst[1].y = v.w;
    };

    auto loadpair = [&](f2 (&dA)[8], f2 (&dB)[8], int row) {
        const float4* v0 = (const float4*)(xb + (size_t)row * TAPS_ + qb);
        const float4* v1 = (const float4*)(xb + (size_t)(row + 1) * TAPS_ + qb);
        #pragma unroll
        for (int j4 = 0; j4 < 4; ++j4) {
            unpack4(&dA[2*j4], v0[j4]);
            unpack4(&dB[2*j4], v1[j4]);
        }
    };

    // 4 rotating row-pairs. Round k uses pair k&3 as (x0,x1); pair (k+1)&3 as
    // (x2,x3) for the fused next-dots; prefetches rows t+6,t+7 into (k+3)&3.
    f2 P0a[8], P0b[8], P1a[8], P1b[8], P2a[8], P2b[8], P3a[8], P3b[8];
    loadpair(P0a, P0b, 0);
    loadpair(P1a, P1b, 2);
    loadpair(P2a, P2b, 4);

    // loop-carried reduced row values (produced by prologue / fused phase).
    float qxrS, xqrS, urS, vrS, wy0S, wy1S;

    // ---- prologue: round 0's exchange data, R12 pre-phase bit-for-bit ----
    {
        f2 qx2 = pk2(0.f), xq2 = pk2(0.f), u2 = pk2(0.f), v2 = pk2(0.f);
        #pragma unroll
        for (int j = 0; j < 8; ++j) {
            qx2 = __builtin_elementwise_fma(Q[j],  P0a[j], qx2);
            xq2 = __builtin_elementwise_fma(QT[j], P0a[j], xq2);
            u2  = __builtin_elementwise_fma(Q[j],  P0b[j], u2);
            v2  = __builtin_elementwise_fma(QT[j], P0b[j], v2);
        }
        qxrS = quad_reduce(qx2.x + qx2.y);
        xqrS = quad_reduce(xq2.x + xq2.y);
        urS  = quad_reduce(u2.x + u2.y);
        vrS  = quad_reduce(v2.x + v2.y);
        bufs[0][q][r] = (q == 0) ? qxrS : (q == 1) ? xqrS : (q == 2) ? urS : vrS;

        f2 wy02 = pk2(0.f), wy12 = pk2(0.f);
        #pragma unroll
        for (int j = 0; j < 8; ++j) {
            wy02 = __builtin_elementwise_fma(w[j], P0a[j], wy02);
            wy12 = __builtin_elementwise_fma(w[j], P0b[j], wy12);
        }
        wy0S = quad_reduce(wy02.x + wy02.y);
        wy1S = quad_reduce(wy12.x + wy12.y);
    }

    auto round = [&](int t, f2 (&x0)[8], f2 (&x1)[8],
                     f2 (&xn0)[8], f2 (&xn1)[8],
                     f2 (&xf0)[8], f2 (&xf1)[8],
                     int par, bool pf, bool fuse)
    {
        lds_barrier();   // round's exchange data (written last round) visible

        const float2 l0 = lam2[t];
        const float2 l1 = lam2[t + 1];
        const float2 dd = *(const float2*)&d_lds[t];

        // ---- deep prefetch: rows t+6,t+7 (consumed 2.5 rounds later) ----
        if (pf) loadpair(xf0, xf1, t + 6);

        // ---- read back quarters of Qx, xQ, u, v ----
        f2 Qxq[8], xQq[8], uq[8], vq[8];
        {
            const float4* p0 = (const float4*)(&bufs[par][0][qb]);
            const float4* p1 = (const float4*)(&bufs[par][1][qb]);
            const float4* p2 = (const float4*)(&bufs[par][2][qb]);
            const float4* p3 = (const float4*)(&bufs[par][3][qb]);
            #pragma unroll
            for (int j4 = 0; j4 < 4; ++j4) {
                unpack4(&Qxq[2*j4], p0[j4]);
                unpack4(&xQq[2*j4], p1[j4]);
                unpack4(&uq [2*j4], p2[j4]);
                unpack4(&vq [2*j4], p3[j4]);
            }
        }

        // ---- post-barrier dots: pd0=x0.Qx, a=x1.xQ, bb=x1.Qx, c2=x1.u ----
        f2 pd2 = pk2(0.f), a2 = pk2(0.f), bb2 = pk2(0.f), c22 = pk2(0.f);
        #pragma unroll
        for (int j = 0; j < 8; ++j) {
            pd2 = __builtin_elementwise_fma(x0[j], Qxq[j], pd2);
            a2  = __builtin_elementwise_fma(x1[j], xQq[j], a2);
            bb2 = __builtin_elementwise_fma(x1[j], Qxq[j], bb2);
            c22 = __builtin_elementwise_fma(x1[j], uq[j],  c22);
        }
        const float pd0 = quad_reduce(pd2.x + pd2.y);
        const float a   = quad_reduce(a2.x + a2.y);
        const float bb  = quad_reduce(bb2.x + bb2.y);
        const float c2  = quad_reduce(c22.x + c22.y);

        // ---- scalars (R12 op order, rcp_nr on dens) ----
        const float den0 = fmaf(sig, pd0, l0.x);
        const float s0   = sig * rcp_nr(den0);
        const float err0 = dd.x - wy0S;
        const float es0  = s0 * err0;
        const float sa   = s0 * a;
        const float sb   = s0 * bb;

        const float sig1 = sig * l0.y;
        const float pd1  = fmaf(-sa, bb, c2);
        const float den1 = fmaf(sig1, pd1, l1.x);
        const float s1   = sig1 * rcp_nr(den1);
        const float y1   = fmaf(es0, bb, wy1S);
        const float err1 = dd.y - y1;
        const float es1  = s1 * err1;
        sig = sig1 * l1.y;

        if (tid == 0)
            *(float2*)(y_out + (size_t)b * N_ + t) = make_float2(wy0S, y1);

        // ---- explicit dual rank-1 updates (R12 bits) fused with next-dots ----
        const float qx1r = fmaf(-sa, qxrS, urS);
        const float xq1r = fmaf(-sb, xqrS, vrS);
        const f2 nsa   = pk2(-sa);
        const f2 nsb   = pk2(-sb);
        const f2 s0v   = pk2(s0);
        const f2 s1v   = pk2(s1);
        const f2 es0v  = pk2(es0);
        const f2 es1v  = pk2(es1);
        const f2 ntr0  = pk2(-(s0 * qxrS));
        const f2 ntr1  = pk2(-(s1 * qx1r));
        const f2 nxqr  = pk2(-xqrS);
        const f2 nxq1r = pk2(-xq1r);

        f2 nqx = pk2(0.f), nxq = pk2(0.f), nu = pk2(0.f), nv = pk2(0.f);
        f2 nw0 = pk2(0.f), nw1 = pk2(0.f);

        #pragma unroll
        for (int j = 0; j < 8; ++j) {
            const f2 Qx1 = __builtin_elementwise_fma(nsa, Qxq[j], uq[j]);
            const f2 xQ1 = __builtin_elementwise_fma(nsb, xQq[j], vq[j]);
            const f2 tq0 = s0v * Qxq[j];
            const f2 tq1 = s1v * Qx1;
            // w: two honest rank-1 adds
            w[j] = __builtin_elementwise_fma(Qxq[j], es0v, w[j]);
            w[j] = __builtin_elementwise_fma(Qx1,    es1v, w[j]);
            // Q row r: subtract both outer-product terms
            Q[j] = __builtin_elementwise_fma(ntr0, xQq[j], Q[j]);
            Q[j] = __builtin_elementwise_fma(ntr1, xQ1,    Q[j]);
            // QT row r (= Q column r): transposed products, identical bits
            QT[j] = __builtin_elementwise_fma(tq0, nxqr,  QT[j]);
            QT[j] = __builtin_elementwise_fma(tq1, nxq1r, QT[j]);
            // fused next-round pre-dots on the freshly updated registers
            // (same values/op-order as R12's separate pre-dot pass)
            if (fuse) {
                nqx = __builtin_elementwise_fma(Q[j],  xn0[j], nqx);
                nxq = __builtin_elementwise_fma(QT[j], xn0[j], nxq);
                nu  = __builtin_elementwise_fma(Q[j],  xn1[j], nu);
                nv  = __builtin_elementwise_fma(QT[j], xn1[j], nv);
                nw0 = __builtin_elementwise_fma(w[j],  xn0[j], nw0);
                nw1 = __builtin_elementwise_fma(w[j],  xn1[j], nw1);
            }
        }

        if (fuse) {
            qxrS = quad_reduce(nqx.x + nqx.y);
            xqrS = quad_reduce(nxq.x + nxq.y);
            urS  = quad_reduce(nu.x + nu.y);
            vrS  = quad_reduce(nv.x + nv.y);
            bufs[par ^ 1][q][r] =
                (q == 0) ? qxrS : (q == 1) ? xqrS : (q == 2) ? urS : vrS;
            wy0S = quad_reduce(nw0.x + nw0.y);
            wy1S = quad_reduce(nw1.x + nw1.y);
        }
    };

    // main loop: rounds k=0..995 (t=0..1990), 4-round unroll for pair rotation.
    // round k: x=pair k&3, xn=pair (k+1)&3, prefetch rows t+6,t+7 -> (k+3)&3.
    for (int t = 0; t < 1992; t += 8) {
        round(t + 0, P0a, P0b, P1a, P1b, P3a, P3b, 0, true, true);
        round(t + 2, P1a, P1b, P2a, P2b, P0a, P0b, 1, true, true);
        round(t + 4, P2a, P2b, P3a, P3b, P1a, P1b, 0, true, true);
        round(t + 6, P3a, P3b, P0a, P0b, P2a, P2b, 1, true, true);
    }
    // k=996 (t=1992): prefetch rows 1998,1999 (last valid)
    round(1992, P0a, P0b, P1a, P1b, P3a, P3b, 0, true,  true);
    // k=997 (t=1994): no prefetch
    round(1994, P1a, P1b, P2a, P2b, P0a, P0b, 1, false, true);
    // k=998 (t=1996): fused dots for round 999 (rows 1998,1999 in P3)
    round(1996, P2a, P2b, P3a, P3b, P1a, P1b, 0, false, true);
    // k=999 (t=1998): final round, no prefetch, no fusion
    round(1998, P3a, P3b, P0a, P0b, P2a, P2b, 1, false, false);

    // ---- final weights: row-group 0 holds a full replica across q ----
    if (r == 0) {
        float4* wo = (float4*)(w_out + (size_t)b * TAPS_ + qb);
        #pragma unroll
        for (int j4 = 0; j4 < 4; ++j4)
            wo[j4] = make_float4(w[2*j4].x, w[2*j4].y, w[2*j4+1].x, w[2*j4+1].y);
    }
}

extern "C" void kernel_launch(void* const* d_in, const int* in_sizes, int n_in,
                              void* d_out, int out_size, void* d_ws, size_t ws_size,
                              hipStream_t stream) {
    const float* x_seq   = (const float*)d_in[0];
    const float* d_seq   = (const float*)d_in[1];
    const float* lambdas = (const float*)d_in[2];

    float* y_out = (float*)d_out;                      // B*N floats
    float* w_out = (float*)d_out + (size_t)B_ * N_;    // B*TAPS floats

    rls_kernel<<<B_, 256, 0, stream>>>(x_seq, d_seq, lambdas, y_out, w_out);
}